// Round 5
// baseline (50.137 us; speedup 1.0000x reference)
//
#include <hip/hip_runtime.h>

#define B_TOT   4096
#define NSTEPS  4
#define E       128
#define OUT_DIM 16
#define NMOD    64
#define KSPLIT  8
#define TILE    16

// ws layout:
//   int  cnt [4][64]        at int-offset 0
//   int  off [4][64]        at int-offset 256
//   int  perm[4][4096]      at int-offset 512
//   uint xbufP[4096][128]   at byte 67584   (2 MB, packed bf16 hi<<16|lo)
//   uint4 Wfrag[64][2][4][128][4] at byte 2164736 (4 MB, frag-major bf16)
#define XBUF_BYTE  67584
#define WFRAG_BYTE 2164736

using frag8 = __attribute__((ext_vector_type(8))) short;   // 8 bf16
using f32x4 = __attribute__((ext_vector_type(4))) float;

__device__ __forceinline__ unsigned short f2bf(float x) {
    union { float f; unsigned u; } v; v.f = x;
    unsigned r = v.u + 0x7FFFu + ((v.u >> 16) & 1u);
    return (unsigned short)(r >> 16);
}
__device__ __forceinline__ float bf2f(unsigned short h) {
    union { unsigned u; float f; } v; v.u = ((unsigned)h) << 16;
    return v.f;
}
__device__ __forceinline__ unsigned pack2(unsigned short a, unsigned short b) {
    return (unsigned)a | ((unsigned)b << 16);
}
__device__ __forceinline__ frag8 u4frag(uint4 u) {
    union { uint4 u; frag8 f; } v; v.u = u; return v.f;
}
__device__ __forceinline__ float tanh_fast(float x) {
    return 1.0f - 2.0f / (__expf(2.0f * x) + 1.0f);
}

// blocks 0..3: per-step counting sort.  blocks 4..67: W -> bf16 hi/lo frag-major.
__global__ __launch_bounds__(1024) void prep_sort_kernel(
    const int* __restrict__ mids, const float* __restrict__ W, int* __restrict__ ws)
{
    const int t = threadIdx.x;
    if (blockIdx.x < NSTEPS) {
        const int s = blockIdx.x;
        __shared__ int h[NMOD];
        __shared__ int o[NMOD];
        if (t < NMOD) h[t] = 0;
        __syncthreads();
        for (int b = t; b < B_TOT; b += 1024)
            atomicAdd(&h[mids[b * NSTEPS + s]], 1);
        __syncthreads();
        if (t == 0) {
            int run = 0;
            for (int m = 0; m < NMOD; ++m) { o[m] = run; run += h[m]; }
        }
        __syncthreads();
        if (t < NMOD) {
            ws[s * NMOD + t]       = h[t];
            ws[256 + s * NMOD + t] = o[t];
            h[t] = o[t];
        }
        __syncthreads();
        int* perm = ws + 512 + s * B_TOT;
        for (int b = t; b < B_TOT; b += 1024) {
            const int m = mids[b * NSTEPS + s];
            const int p = atomicAdd(&h[m], 1);
            perm[p] = b;
        }
    } else {
        const int m = blockIdx.x - NSTEPS;
        uint4* __restrict__ wf = (uint4*)((char*)ws + WFRAG_BYTE);
        const f32x4* __restrict__ wg = (const f32x4*)(W + (size_t)m * E * E);
        #pragma unroll
        for (int i = 0; i < 2; ++i) {
            const int f  = i * 1024 + t;        // fragment id 0..2047
            const int c  = f >> 4;              // W row (output col)
            const int ss = (f >> 2) & 3;        // K chunk of 32
            const int g  = f & 3;               // k-group of 8
            const int fi = (c * E + ss * 32 + g * 8) >> 2;
            const f32x4 v0 = wg[fi];
            const f32x4 v1 = wg[fi + 1];
            const float xf[8] = {v0.x, v0.y, v0.z, v0.w, v1.x, v1.y, v1.z, v1.w};
            unsigned short hh[8], qq[8];
            #pragma unroll
            for (int j = 0; j < 8; ++j) {
                hh[j] = f2bf(xf[j]);
                qq[j] = f2bf(xf[j] - bf2f(hh[j]));
            }
            const uint4 H = { pack2(hh[0], hh[1]), pack2(hh[2], hh[3]),
                              pack2(hh[4], hh[5]), pack2(hh[6], hh[7]) };
            const uint4 L = { pack2(qq[0], qq[1]), pack2(qq[2], qq[3]),
                              pack2(qq[4], qq[5]), pack2(qq[6], qq[7]) };
            const int u = m * 4096 + ss * 512 + c * 4 + g;
            wf[u]        = H;   // hi part
            wf[u + 2048] = L;   // lo part
        }
    }
}

template <bool FIRST, bool LAST>
__global__ __launch_bounds__(256) void step_kernel(
    const int s,
    const int* __restrict__ ws,
    const int* __restrict__ author_ids,
    const float* __restrict__ embed,
    const float* __restrict__ bias,
    const float* __restrict__ cls_W,
    const float* __restrict__ cls_b,
    float* __restrict__ out)
{
    const int m = blockIdx.x >> 3;
    const int k = blockIdx.x & (KSPLIT - 1);
    const int cnt = ws[s * NMOD + m];
    const int off = ws[256 + s * NMOD + m];
    const int start = off + k * TILE;
    const int end   = off + cnt;
    if (start >= end) return;            // uniform across block

    const int t  = threadIdx.x;
    const int w  = t >> 6;
    const int l  = t & 63;
    const int g  = l >> 4;
    const int r0 = l & 15;
    const int c0 = 32 * w + r0;
    const int c1 = c0 + 16;

    const int* __restrict__ perm = ws + 512 + s * B_TOT;
    unsigned* __restrict__ xbufP = (unsigned*)((char*)ws + XBUF_BYTE);
    const uint4* __restrict__ wf = (const uint4*)((char*)ws + WFRAG_BYTE) + m * 4096;

    const float b0 = bias[m * E + c0];
    const float b1 = bias[m * E + c1];

    __shared__ __align__(16) float Yl[LAST ? TILE * (E + 4) : 1];

    for (int base = start; base < end; base += KSPLIT * TILE) {
        const int nb = min(TILE, end - base);

        // ---- A fragments (row r0), direct from global ----
        const bool rok = r0 < nb;
        const int pa = perm[min(base + r0, B_TOT - 1)];
        frag8 ahi[4], alo[4];
        if (FIRST) {
            const f32x4* __restrict__ src =
                (const f32x4*)(embed + (size_t)author_ids[pa] * E);
            #pragma unroll
            for (int ss = 0; ss < 4; ++ss) {
                f32x4 v0 = {0.f, 0.f, 0.f, 0.f}, v1 = {0.f, 0.f, 0.f, 0.f};
                if (rok) { v0 = src[8 * ss + 2 * g]; v1 = src[8 * ss + 2 * g + 1]; }
                const float xf[8] = {v0.x, v0.y, v0.z, v0.w, v1.x, v1.y, v1.z, v1.w};
                #pragma unroll
                for (int j = 0; j < 8; ++j) {
                    const unsigned short hh = f2bf(xf[j]);
                    ahi[ss][j] = (short)hh;
                    alo[ss][j] = (short)f2bf(xf[j] - bf2f(hh));
                }
            }
        } else {
            const uint4* __restrict__ src = (const uint4*)(xbufP + (size_t)pa * E);
            #pragma unroll
            for (int ss = 0; ss < 4; ++ss) {
                uint4 p0 = {0, 0, 0, 0}, p1 = {0, 0, 0, 0};
                if (rok) { p0 = src[8 * ss + 2 * g]; p1 = src[8 * ss + 2 * g + 1]; }
                const unsigned pv[8] = {p0.x, p0.y, p0.z, p0.w, p1.x, p1.y, p1.z, p1.w};
                #pragma unroll
                for (int j = 0; j < 8; ++j) {
                    ahi[ss][j] = (short)(pv[j] >> 16);
                    alo[ss][j] = (short)(pv[j] & 0xFFFFu);
                }
            }
        }

        // ---- MFMA, B-fragments straight from L2 (coalesced 1KB/wave) ----
        f32x4 acc0 = {0.f, 0.f, 0.f, 0.f};
        f32x4 acc1 = {0.f, 0.f, 0.f, 0.f};
        #pragma unroll
        for (int ss = 0; ss < 4; ++ss) {
            const int u0 = ss * 512 + c0 * 4 + g;
            const int u1 = ss * 512 + c1 * 4 + g;
            const frag8 bh0 = u4frag(wf[u0]);
            const frag8 bq0 = u4frag(wf[u0 + 2048]);
            const frag8 bh1 = u4frag(wf[u1]);
            const frag8 bq1 = u4frag(wf[u1 + 2048]);
            acc0 = __builtin_amdgcn_mfma_f32_16x16x32_bf16(ahi[ss], bh0, acc0, 0, 0, 0);
            acc0 = __builtin_amdgcn_mfma_f32_16x16x32_bf16(alo[ss], bh0, acc0, 0, 0, 0);
            acc0 = __builtin_amdgcn_mfma_f32_16x16x32_bf16(ahi[ss], bq0, acc0, 0, 0, 0);
            acc1 = __builtin_amdgcn_mfma_f32_16x16x32_bf16(ahi[ss], bh1, acc1, 0, 0, 0);
            acc1 = __builtin_amdgcn_mfma_f32_16x16x32_bf16(alo[ss], bh1, acc1, 0, 0, 0);
            acc1 = __builtin_amdgcn_mfma_f32_16x16x32_bf16(ahi[ss], bq1, acc1, 0, 0, 0);
        }

        // ---- epilogue: D row = 4g + r, cols c0/c1 ----
        if (!LAST) {
            #pragma unroll
            for (int r = 0; r < 4; ++r) {
                const int row = 4 * g + r;
                if (row < nb) {
                    const int rb = perm[base + row];
                    const float y0 = tanh_fast(acc0[r] + b0);
                    const float y1 = tanh_fast(acc1[r] + b1);
                    const unsigned short h0 = f2bf(y0);
                    const unsigned short h1 = f2bf(y1);
                    unsigned* __restrict__ dst = xbufP + (size_t)rb * E;
                    dst[c0] = pack2(f2bf(y0 - bf2f(h0)), h0);
                    dst[c1] = pack2(f2bf(y1 - bf2f(h1)), h1);
                }
            }
        } else {
            #pragma unroll
            for (int r = 0; r < 4; ++r) {
                const int row = 4 * g + r;
                Yl[row * (E + 4) + c0] = acc0[r] + b0;
                Yl[row * (E + 4) + c1] = acc1[r] + b1;
            }
            __syncthreads();
            const int row = t >> 4, j = t & 15;
            if (row < nb) {
                const f32x4* __restrict__ cw = (const f32x4*)(cls_W + j * E);
                float a2 = cls_b[j];
                #pragma unroll 8
                for (int jj = 0; jj < 32; ++jj) {
                    const f32x4 y4 = *(const f32x4*)&Yl[row * (E + 4) + jj * 4];
                    const f32x4 w4 = cw[jj];
                    a2 += y4.x * w4.x + y4.y * w4.y + y4.z * w4.z + y4.w * w4.w;
                }
                out[(size_t)perm[base + row] * OUT_DIM + j] = a2;
            }
            __syncthreads();   // Yl free for next tile
        }
    }
}

extern "C" void kernel_launch(void* const* d_in, const int* in_sizes, int n_in,
                              void* d_out, int out_size, void* d_ws, size_t ws_size,
                              hipStream_t stream) {
    const int*   author_ids = (const int*)d_in[0];
    const int*   module_ids = (const int*)d_in[1];
    const float* embed      = (const float*)d_in[2];
    const float* W          = (const float*)d_in[3];
    const float* bias       = (const float*)d_in[4];
    const float* cls_W      = (const float*)d_in[5];
    const float* cls_b      = (const float*)d_in[6];
    float* out = (float*)d_out;
    int*   wsI = (int*)d_ws;

    prep_sort_kernel<<<NSTEPS + NMOD, 1024, 0, stream>>>(module_ids, W, wsI);

    const dim3 g(NMOD * KSPLIT), blk(256);
    step_kernel<true,  false><<<g, blk, 0, stream>>>(0, wsI, author_ids, embed, bias, cls_W, cls_b, out);
    step_kernel<false, false><<<g, blk, 0, stream>>>(1, wsI, author_ids, embed, bias, cls_W, cls_b, out);
    step_kernel<false, false><<<g, blk, 0, stream>>>(2, wsI, author_ids, embed, bias, cls_W, cls_b, out);
    step_kernel<false, true ><<<g, blk, 0, stream>>>(3, wsI, author_ids, embed, bias, cls_W, cls_b, out);
}